// Round 4
// baseline (326.099 us; speedup 1.0000x reference)
//
#include <hip/hip_runtime.h>

// NLSearch: B=1, T=4, C=64 (2 heads x 32ch), H=W=192, stride0=4 -> 48x48 queries,
// patch 7x7, offsets dt{-1,0,1} x di,dj{-3..4} (L=192), top-K=7.
// Out: vals f32 [2][9216][7] (129024) then inds [2][9216][7][3] (387072).
//
// R12 (from R11 counters: nls_fast 244.3us, VALUBusy 55%, VGPR 124, HBM 2.5%):
//  R11 cut ~11us of VALU work but only ~5.5us of time -> cutting instructions
//  converts busy->idle. The 45% idle at fixed occupancy (4 waves/SIMD) with
//  near-zero HBM/LDS pressure points at dependent-FMA issue bubbles: source
//  order dip->djp->x gives each acc 7 back-to-back dependent FMAs (4cy dep
//  latency vs 2cy issue = 50% bubble if the scheduler doesn't interleave).
//  SINGLE CHANGE: FMA_BLOCK reordered x-OUTERMOST so 16 independent acc
//  chains interleave (32 issue-cy between dependent uses). Per-acc op order
//  unchanged (x=0..6 ascending, mul-init still first touch) -> bit-identical.
//
// Hard-won lessons kept:
//  - NO min-waves arg in __launch_bounds__ (R3: VGPR cap -> 3.1GB scratch).
//  - A-patch loads must be coalesced-from-transposed (R8: +27us).
//  - Rolled dtI loop (R10: neutral, keeps I$ small). I$ thrash theory dead.
//  - merge-tree reduce + continuous 2-buffer prefetch + mul-init (R11: -5.5us).
//  - Fallback to the proven R5 LDS kernel if ws_size < 75.5 MB (untouched).

#define HH 192
#define WW 192
#define HW (HH * WW)
#define TSLICE (192 * 192 * 64)   // one t-slice of a transposed video (floats)
#define ROWST  (192 * 64)         // h-row stride in transposed layout (floats)
#define TVID   (4 * TSLICE)

__device__ __forceinline__ int reflect_i(int idx, int n) {
    idx = idx < 0 ? -idx : idx;
    idx = idx >= n ? 2 * (n - 1) - idx : idx;
    return idx;
}

template <int CTRL>
__device__ __forceinline__ float dpp_add(float x) {
    int y = __builtin_amdgcn_update_dpp(0, __float_as_int(x), CTRL, 0xf, 0xf, true);
    return x + __int_as_float(y);
}

template <int PAT>
__device__ __forceinline__ float swz_add(float x) {
    int y = __builtin_amdgcn_ds_swizzle(__float_as_int(x), PAT);
    return x + __int_as_float(y);
}

// lane31 <- sum(lanes 0..31), lane63 <- sum(lanes 32..63); VALU pipe, no LDS.
// (kept for the fallback kernel)
__device__ __forceinline__ float reduce32(float v) {
    v = dpp_add<0x111>(v);  // row_shr:1
    v = dpp_add<0x112>(v);  // row_shr:2
    v = dpp_add<0x114>(v);  // row_shr:4
    v = dpp_add<0x118>(v);  // row_shr:8
    v = dpp_add<0x142>(v);  // row_bcast15
    return v;
}

// Merge-tree reduction over 32 lanes (per 32-half) of 16 accumulators.
// Returns S: lane L holds full 32-sum of acc[L & 15] for its half.
__device__ __forceinline__ float merge_reduce(const float* acc,
                                              bool b0, bool b1, bool b2, bool b3) {
    float u[8];
    #pragma unroll
    for (int j = 0; j < 8; ++j) {
        float e = dpp_add<0xB1>(acc[2 * j]);
        float o = dpp_add<0xB1>(acc[2 * j + 1]);
        u[j] = b0 ? o : e;
    }
    float v[4];
    #pragma unroll
    for (int i = 0; i < 4; ++i) {
        float e = dpp_add<0x4E>(u[2 * i]);
        float o = dpp_add<0x4E>(u[2 * i + 1]);
        v[i] = b1 ? o : e;
    }
    float w[2];
    #pragma unroll
    for (int m = 0; m < 2; ++m) {
        float e = swz_add<0x101F>(v[2 * m]);
        float o = swz_add<0x101F>(v[2 * m + 1]);
        w[m] = b2 ? o : e;
    }
    float s0 = swz_add<0x201F>(w[0]);
    float s1 = swz_add<0x201F>(w[1]);
    float S  = b3 ? s1 : s0;
    return swz_add<0x401F>(S);
}

// ---------------- transpose [t][c][h][w] -> [t][h][w][c], both vids ----------
__global__ __launch_bounds__(256) void transpose_k(
    const float* __restrict__ v0, const float* __restrict__ v1,
    float* __restrict__ ws)
{
    __shared__ float tile[64 * 65];
    const int wt  = blockIdx.x;      // 0..2  (w tile of 64)
    const int h   = blockIdx.y;      // 0..191
    const int z   = blockIdx.z;      // vid*4 + t
    const int vid = z >> 2;
    const int t   = z & 3;
    const int w0  = wt * 64;
    const int tid = threadIdx.x;
    const int a   = tid & 63;
    const int g   = tid >> 6;
    const float* src = (vid ? v1 : v0) + (size_t)t * 64 * HW + h * WW + w0;
    float* dst = ws + (size_t)vid * TVID + ((size_t)(t * 192 + h) * 192 + w0) * 64;
    #pragma unroll
    for (int cc = g; cc < 64; cc += 4)
        tile[cc * 65 + a] = src[(size_t)cc * HW + a];
    __syncthreads();
    #pragma unroll
    for (int ww = g; ww < 64; ww += 4)
        dst[ww * 64 + a] = tile[a * 65 + ww];
}

// ---------------- main kernel: barrier-free, continuous-stream prefetch -----
__global__ __launch_bounds__(256) void nls_fast(
    const float* __restrict__ T0,
    const float* __restrict__ T1,
    float* __restrict__ out)
{
    __shared__ float score[2 * 192];

    // XCD swizzle: xcd = blk&7 -> qi band of 6; inner (hd, t, qi_l, qjp fastest)
    const int b    = blockIdx.x;
    const int xcd  = b & 7;
    const int loc  = b >> 3;
    const int qjp  = loc % 24;
    const int r1   = loc / 24;
    const int qi_l = r1 % 6;
    const int r2   = r1 / 6;
    const int t    = r2 & 3;
    const int hd   = r2 >> 2;
    const int qi   = xcd * 6 + qi_l;

    const int qh  = qi * 4;
    const int qw0 = qjp * 8;

    const int tid  = threadIdx.x;
    const int lane = tid & 63;
    const int wid  = tid >> 6;

    const int c     = lane & 31;
    const int hhalf = lane >> 5;   // dj half: 0 -> dj 0..3, 1 -> dj 4..7
    const int q     = wid >> 1;    // query in pair
    const int d     = wid & 1;     // di half: rows 4d..4d+3
    const int cg    = hd * 32 + c;
    const int qwq   = qw0 + 4 * q;

    // merge-reduce lane constants
    const bool b0 = (lane & 1) != 0;
    const bool b1 = (lane & 2) != 0;
    const bool b2 = (lane & 4) != 0;
    const bool b3 = (lane & 8) != 0;
    const bool writer = (lane & 16) == 0;   // lanes 0-15 and 32-47
    const int  kL   = lane & 15;
    const int  svoff = q * 192 + (4 * d + (kL >> 2)) * 8 + 4 * hhalf + (kL & 3);

    // ---- A patch -> regs (coalesced: 32 contiguous c per half-wave) ----
    float a[7][7];
    {
        #pragma unroll
        for (int y = 0; y < 7; ++y) {
            const int hv = reflect_i(qh - 3 + y, HH);
            const float* rp = T0 + (size_t)(t * 192 + hv) * ROWST + cg;
            #pragma unroll
            for (int x = 0; x < 7; ++x) {
                const int wv = reflect_i(qwq - 3 + x, WW);
                a[y][x] = rp[wv * 64];
            }
        }
    }

    const bool interior = (qi >= 2) && (qi <= 46) && (qjp >= 1) && (qjp <= 22);

    // exterior w-offsets (block-constant across tp)
    int wo[10];
    #pragma unroll
    for (int v = 0; v < 10; ++v)
        wo[v] = reflect_i(qwq - 6 + 4 * hhalf + v, WW) * 64 + cg;

    // R12: x-OUTERMOST so consecutive FMAs hit 16 different accs (no dep
    // bubbles). Per-acc order unchanged (x ascending; mul-init first touch)
    // -> bit-identical scores.
#define FMA_BLOCK(RWBUF)                                                 \
    {                                                                    \
        const int dlo = r > 6 ? r - 6 : 0;                               \
        const int dhi = r < 3 ? r : 3;                                   \
        _Pragma("unroll")                                                \
        for (int x = 0; x < 7; ++x) {                                    \
            _Pragma("unroll")                                            \
            for (int dip = 0; dip < 4; ++dip) {                          \
                if (dip >= dlo && dip <= dhi) {                          \
                    const int y = r - dip;                               \
                    _Pragma("unroll")                                    \
                    for (int djp = 0; djp < 4; ++djp) {                  \
                        if (y == 0 && x == 0)                            \
                            acc[dip * 4 + djp] = a[0][0] * (RWBUF)[djp]; \
                        else                                             \
                            acc[dip * 4 + djp] =                         \
                                fmaf(a[y][x], (RWBUF)[djp + x], acc[dip * 4 + djp]); \
                    }                                                    \
                }                                                        \
            }                                                            \
        }                                                                \
    }

    // ---- continuous row stream: rows of distinct tps are consecutive ----
    float rwb[2][10];
    float acc[16];
    float S = 0.f;

    const int tp0 = (t > 0) ? t - 1 : 0;

    // preload row 0 of tp0
    if (interior) {
        const float* P0 = T1 + (size_t)(tp0 * 192 + qh - 6 + 4 * d) * ROWST
                        + (qwq - 6 + 4 * hhalf) * 64 + cg;
        #pragma unroll
        for (int v = 0; v < 10; ++v) rwb[0][v] = P0[v * 64];
    } else {
        const int hv0 = reflect_i(qh - 6 + 4 * d, HH);
        const float* pr = T1 + (size_t)tp0 * TSLICE + (size_t)hv0 * ROWST;
        #pragma unroll
        for (int v = 0; v < 10; ++v) rwb[0][v] = pr[wo[v]];
    }

    int tprev = -1;
    #pragma unroll 1
    for (int dtI = 0; dtI < 3; ++dtI) {
        int tp = t + dtI - 1;
        tp = tp < 0 ? 0 : (tp > 3 ? 3 : tp);

        if (tp != tprev) {
            tprev = tp;

            if (interior) {
                const float* P = T1 + (size_t)(tp * 192 + qh - 6 + 4 * d) * ROWST
                               + (qwq - 6 + 4 * hhalf) * 64 + cg;
                const float* Pn0 = P + (tp < 3 ? TSLICE : 0);  // next tp, row 0
                #pragma unroll
                for (int r = 0; r < 10; ++r) {
                    const float* nrp = (r < 9) ? (P + (size_t)(r + 1) * ROWST) : Pn0;
                    #pragma unroll
                    for (int v = 0; v < 10; ++v)
                        rwb[(r + 1) & 1][v] = nrp[v * 64];
                    FMA_BLOCK(rwb[r & 1])
                }
            } else {
                const float* Ptb = T1 + (size_t)tp * TSLICE;
                const float* Ptn = (tp < 3) ? (Ptb + TSLICE) : Ptb;
                #pragma unroll
                for (int r = 0; r < 10; ++r) {
                    const int nr = (r < 9) ? r + 1 : 0;
                    const float* nb = (r < 9) ? Ptb : Ptn;
                    const int hv = reflect_i(qh - 6 + 4 * d + nr, HH);
                    const float* pr = nb + (size_t)hv * ROWST;
                    #pragma unroll
                    for (int v = 0; v < 10; ++v)
                        rwb[(r + 1) & 1][v] = pr[wo[v]];
                    FMA_BLOCK(rwb[r & 1])
                }
            }

            // c-reduction: lane L ends with 32-sum of acc[L&15] for its half
            S = merge_reduce(acc, b0, b1, b2, b3);
        }

        // write this dt's slot (dup dt writes same register -> exact ties)
        if (writer) score[svoff + dtI * 64] = S;
    }
#undef FMA_BLOCK

    __syncthreads();

    // ---- top-K=7 over 192 per query; waves 0,1 ----
    if (wid < 2) {
        const int qq = wid;
        const int qj = 2 * qjp + qq;
        float v0 = score[qq * 192 + lane];
        float v1 = score[qq * 192 + 64 + lane];
        float v2 = score[qq * 192 + 128 + lane];
        const int qglob = (t * 48 + qi) * 48 + qj;
        const int vbase = (hd * 9216 + qglob) * 7;
        const int ibase = 129024 + vbase * 3;
        for (int r = 0; r < 7; ++r) {
            float bv = v0; int bi = lane;
            if (v1 > bv) { bv = v1; bi = lane + 64; }
            if (v2 > bv) { bv = v2; bi = lane + 128; }
            #pragma unroll
            for (int m = 1; m <= 32; m <<= 1) {
                float ov = __shfl_xor(bv, m);
                int   oi = __shfl_xor(bi, m);
                if (ov > bv || (ov == bv && oi < bi)) { bv = ov; bi = oi; }
            }
            if (lane == 0) {
                out[vbase + r] = bv;
                int dtSel = bi >> 6;
                int rr    = bi & 63;
                int diSel = (rr >> 3) - 3;
                int djSel = (rr & 7) - 3;
                int ts = t + dtSel - 1;
                ts = ts < 0 ? 0 : (ts > 3 ? 3 : ts);
                int hs = reflect_i(qh + diSel, HH);
                int ws = reflect_i(qj * 4 + djSel, WW);
                float* op = out + ibase + 3 * r;
                op[0] = (float)ts;
                op[1] = (float)hs;
                op[2] = (float)ws;
            }
            if ((bi & 63) == lane) {
                int slot = bi >> 6;
                if (slot == 0)      v0 = -3.4e38f;
                else if (slot == 1) v1 = -3.4e38f;
                else                v2 = -3.4e38f;
            }
        }
    }
}

// ---------------- fallback (proven R5 kernel, 331 us) if ws too small --------
#define BS_CSTR 282
#define BS_SZ   (32 * BS_CSTR)
#define AF_CSTR 86

__global__ __launch_bounds__(256) void nls_kernel(
    const float* __restrict__ vid0,
    const float* __restrict__ vid1,
    float* __restrict__ out)
{
    __shared__ float smem[BS_SZ + 2 * 192];
    float* Bs = smem;
    float* Asf = smem;
    float* score = smem + BS_SZ;

    const int b    = blockIdx.x;
    const int xcd  = b & 7;
    const int loc  = b >> 3;
    const int qjp  = loc % 24;
    const int r1   = loc / 24;
    const int qi_l = r1 % 6;
    const int r2   = r1 / 6;
    const int t    = r2 & 3;
    const int hd   = r2 >> 2;
    const int qi   = xcd * 6 + qi_l;

    const int qh  = qi * 4;
    const int qw0 = qjp * 8;

    const int tid  = threadIdx.x;
    const int lane = tid & 63;
    const int wid  = tid >> 6;

    const bool intA = (qi >= 1) && (qjp >= 1) && (qjp <= 22);
    const bool intB = (qi >= 2) && (qi <= 46) && (qjp >= 1) && (qjp <= 22);

    if (intA) {
        const int sc = tid & 31;
        const int gg = tid >> 5;
        const float* src = vid0 + (size_t)(t * 64 + hd * 32 + sc) * HW
                         + (qh - 3) * WW + (qw0 - 3);
        float* dstc = Asf + sc * AF_CSTR;
        for (int it = gg; it < 21; it += 8) {
            int u = it / 3, grp = it - u * 3;
            float4 val = *(const float4*)(src + u * WW + 4 * grp);
            float* dp = dstc + u * 12 + 4 * grp;
            *(float2*)(dp)     = make_float2(val.x, val.y);
            *(float2*)(dp + 2) = make_float2(val.z, val.w);
        }
    } else {
        const int sc = tid >> 3;
        const int vl = tid & 7;
        const float* src = vid0 + (size_t)(t * 64 + hd * 32 + sc) * HW;
        const int wa0 = reflect_i(qw0 - 3 + vl, WW);
        const int wa1 = (vl < 4) ? reflect_i(qw0 + 5 + vl, WW) : 0;
        float* dst = Asf + sc * AF_CSTR + vl;
        #pragma unroll
        for (int u = 0; u < 7; ++u) {
            int hh = reflect_i(qh - 3 + u, HH);
            const float* rp = src + hh * WW;
            dst[u * 12] = rp[wa0];
            if (vl < 4) dst[u * 12 + 8] = rp[wa1];
        }
    }
    __syncthreads();

    const int c     = lane & 31;
    const int hhalf = lane >> 5;
    const int q     = wid >> 1;
    const int d     = wid & 1;

    float a[7][8];
    {
        const float* Ab = Asf + c * AF_CSTR + 4 * q;
        #pragma unroll
        for (int y = 0; y < 7; ++y) {
            #pragma unroll
            for (int j = 0; j < 4; ++j)
                *(float2*)&a[y][2 * j] = *(const float2*)(Ab + y * 12 + 2 * j);
        }
    }

    const float* Bc = Bs + c * BS_CSTR + (4 * d) * 20 + 4 * q + 4 * hhalf;

    int tprev = -1;
    #pragma unroll 1
    for (int dtI = 0; dtI < 3; ++dtI) {
        int tp = t + dtI - 1;
        tp = tp < 0 ? 0 : (tp > 3 ? 3 : tp);
        __syncthreads();
        if (tp == tprev) {
            if (tid < 128) {
                int qq = tid >> 6, o = tid & 63;
                score[qq * 192 + dtI * 64 + o] = score[qq * 192 + (dtI - 1) * 64 + o];
            }
            continue;
        }
        tprev = tp;

        if (intB) {
            const int sc = tid & 31;
            const int gg = tid >> 5;
            const float* src = vid1 + (size_t)(tp * 64 + hd * 32 + sc) * HW
                             + (qh - 6) * WW + (qw0 - 6);
            float* dstc = Bs + sc * BS_CSTR;
            for (int it = gg; it < 70; it += 8) {
                int u = it / 5, grp = it - u * 5;
                float4 val = *(const float4*)(src + u * WW + 4 * grp);
                float* dp = dstc + u * 20 + 4 * grp;
                *(float2*)(dp)     = make_float2(val.x, val.y);
                *(float2*)(dp + 2) = make_float2(val.z, val.w);
            }
        } else {
            const int sc = tid >> 3;
            const int vl = tid & 7;
            const float* src = vid1 + (size_t)(tp * 64 + hd * 32 + sc) * HW;
            const int w0 = reflect_i(qw0 - 6 + vl, WW);
            const int w1 = reflect_i(qw0 + 2 + vl, WW);
            const int w2 = (vl < 4) ? reflect_i(qw0 + 10 + vl, WW) : 0;
            float* dst = Bs + sc * BS_CSTR + vl;
            #pragma unroll
            for (int u = 0; u < 14; ++u) {
                int hh2 = reflect_i(qh - 6 + u, HH);
                const float* rp = src + hh2 * WW;
                dst[u * 20]     = rp[w0];
                dst[u * 20 + 8] = rp[w1];
                if (vl < 4) dst[u * 20 + 16] = rp[w2];
            }
        }
        __syncthreads();

        {
            float acc[16];
            #pragma unroll
            for (int k = 0; k < 16; ++k) acc[k] = 0.f;
            #pragma unroll
            for (int r = 0; r < 10; ++r) {
                float rw[12];
                const float* Br = Bc + r * 20;
                #pragma unroll
                for (int j = 0; j < 6; ++j)
                    *(float2*)&rw[2 * j] = *(const float2*)(Br + 2 * j);
                const int dlo = r > 6 ? r - 6 : 0;
                const int dhi = r < 3 ? r : 3;
                #pragma unroll
                for (int dip = 0; dip < 4; ++dip) {
                    if (dip >= dlo && dip <= dhi) {
                        const int y = r - dip;
                        #pragma unroll
                        for (int djp = 0; djp < 4; ++djp)
                            #pragma unroll
                            for (int x = 0; x < 7; ++x)
                                acc[dip * 4 + djp] =
                                    fmaf(a[y][x], rw[djp + x], acc[dip * 4 + djp]);
                    }
                }
            }
            #pragma unroll
            for (int k = 0; k < 16; ++k) acc[k] = reduce32(acc[k]);
            if ((lane & 31) == 31) {
                float* sp = &score[q * 192 + dtI * 64 + 4 * hhalf];
                #pragma unroll
                for (int dip = 0; dip < 4; ++dip) {
                    float* dp = sp + (4 * d + dip) * 8;
                    *(float2*)(dp)     = make_float2(acc[dip * 4 + 0], acc[dip * 4 + 1]);
                    *(float2*)(dp + 2) = make_float2(acc[dip * 4 + 2], acc[dip * 4 + 3]);
                }
            }
        }
    }

    __syncthreads();

    if (wid < 2) {
        const int qq = wid;
        const int qj = 2 * qjp + qq;
        float v0 = score[qq * 192 + lane];
        float v1 = score[qq * 192 + 64 + lane];
        float v2 = score[qq * 192 + 128 + lane];
        const int qglob = (t * 48 + qi) * 48 + qj;
        const int vbase = (hd * 9216 + qglob) * 7;
        const int ibase = 129024 + vbase * 3;
        for (int r = 0; r < 7; ++r) {
            float bv = v0; int bi = lane;
            if (v1 > bv) { bv = v1; bi = lane + 64; }
            if (v2 > bv) { bv = v2; bi = lane + 128; }
            #pragma unroll
            for (int m = 1; m <= 32; m <<= 1) {
                float ov = __shfl_xor(bv, m);
                int   oi = __shfl_xor(bi, m);
                if (ov > bv || (ov == bv && oi < bi)) { bv = ov; bi = oi; }
            }
            if (lane == 0) {
                out[vbase + r] = bv;
                int dtSel = bi >> 6;
                int rr    = bi & 63;
                int diSel = (rr >> 3) - 3;
                int djSel = (rr & 7) - 3;
                int ts = t + dtSel - 1;
                ts = ts < 0 ? 0 : (ts > 3 ? 3 : ts);
                int hs = reflect_i(qh + diSel, HH);
                int ws = reflect_i(qj * 4 + djSel, WW);
                float* op = out + ibase + 3 * r;
                op[0] = (float)ts;
                op[1] = (float)hs;
                op[2] = (float)ws;
            }
            if ((bi & 63) == lane) {
                int slot = bi >> 6;
                if (slot == 0)      v0 = -3.4e38f;
                else if (slot == 1) v1 = -3.4e38f;
                else                v2 = -3.4e38f;
            }
        }
    }
}

extern "C" void kernel_launch(void* const* d_in, const int* in_sizes, int n_in,
                              void* d_out, int out_size, void* d_ws, size_t ws_size,
                              hipStream_t stream) {
    const float* vid0 = (const float*)d_in[0];
    const float* vid1 = (const float*)d_in[1];
    float* out = (float*)d_out;
    const size_t need = 2ull * (size_t)TVID * sizeof(float);   // 75.5 MB
    if (ws_size >= need) {
        float* ws = (float*)d_ws;
        transpose_k<<<dim3(3, 192, 8), 256, 0, stream>>>(vid0, vid1, ws);
        nls_fast<<<dim3(9216), 256, 0, stream>>>(ws, ws + TVID, out);
    } else {
        nls_kernel<<<dim3(9216), 256, 0, stream>>>(vid0, vid1, out);
    }
}

// Round 6
// 320.242 us; speedup vs baseline: 1.0183x; 1.0183x over previous
//
#include <hip/hip_runtime.h>

// NLSearch: B=1, T=4, C=64 (2 heads x 32ch), H=W=192, stride0=4 -> 48x48 queries,
// patch 7x7, offsets dt{-1,0,1} x di,dj{-3..4} (L=192), top-K=7.
// Out: vals f32 [2][9216][7] (129024) then inds [2][9216][7][3] (387072).
//
// R14: R13's asm-prefetch FAILED correctness (absmax 20.5): counted-vmcnt
// math was sound, so the corruption is the rule-18/spill class -- 20 asm-live
// floats likely spilled, and a spill store between issue and s_waitcnt writes
// pre-load garbage. asm loads retired until a spill-proof form exists.
// THIS ROUND: nls_fast reverted VERBATIM to R12 (246.7us, passing). Only
// transpose_k changes: float4 both sides (load: 4x256B segs/wave-instr;
// store: 1KB contiguous/wave-instr), 32->8 global mem insts per thread.
// Total was 326us with nls_fast=246 -> ~80us of transpose+gap vs 24us BW
// floor. Predict total ~285-295, nls_fast counters unchanged.
//
// Hard-won lessons kept:
//  - NO min-waves arg in __launch_bounds__ (R3: VGPR cap -> 3.1GB scratch).
//  - A-patch loads must be coalesced-from-transposed (R8: +27us).
//  - Rolled dtI loop (R10). merge-tree reduce + mul-init (R11). x-outermost
//    FMA order (R12, neutral but free). NO inline-asm loads (R13: corrupt).
//  - Fallback to the proven R5 LDS kernel if ws_size < 75.5 MB (untouched).

#define HH 192
#define WW 192
#define HW (HH * WW)
#define TSLICE (192 * 192 * 64)   // one t-slice of a transposed video (floats)
#define ROWST  (192 * 64)         // h-row stride in transposed layout (floats)
#define TVID   (4 * TSLICE)

__device__ __forceinline__ int reflect_i(int idx, int n) {
    idx = idx < 0 ? -idx : idx;
    idx = idx >= n ? 2 * (n - 1) - idx : idx;
    return idx;
}

template <int CTRL>
__device__ __forceinline__ float dpp_add(float x) {
    int y = __builtin_amdgcn_update_dpp(0, __float_as_int(x), CTRL, 0xf, 0xf, true);
    return x + __int_as_float(y);
}

template <int PAT>
__device__ __forceinline__ float swz_add(float x) {
    int y = __builtin_amdgcn_ds_swizzle(__float_as_int(x), PAT);
    return x + __int_as_float(y);
}

// lane31 <- sum(lanes 0..31), lane63 <- sum(lanes 32..63); VALU pipe, no LDS.
// (kept for the fallback kernel)
__device__ __forceinline__ float reduce32(float v) {
    v = dpp_add<0x111>(v);  // row_shr:1
    v = dpp_add<0x112>(v);  // row_shr:2
    v = dpp_add<0x114>(v);  // row_shr:4
    v = dpp_add<0x118>(v);  // row_shr:8
    v = dpp_add<0x142>(v);  // row_bcast15
    return v;
}

// Merge-tree reduction over 32 lanes (per 32-half) of 16 accumulators.
// Returns S: lane L holds full 32-sum of acc[L & 15] for its half.
__device__ __forceinline__ float merge_reduce(const float* acc,
                                              bool b0, bool b1, bool b2, bool b3) {
    float u[8];
    #pragma unroll
    for (int j = 0; j < 8; ++j) {
        float e = dpp_add<0xB1>(acc[2 * j]);
        float o = dpp_add<0xB1>(acc[2 * j + 1]);
        u[j] = b0 ? o : e;
    }
    float v[4];
    #pragma unroll
    for (int i = 0; i < 4; ++i) {
        float e = dpp_add<0x4E>(u[2 * i]);
        float o = dpp_add<0x4E>(u[2 * i + 1]);
        v[i] = b1 ? o : e;
    }
    float w[2];
    #pragma unroll
    for (int m = 0; m < 2; ++m) {
        float e = swz_add<0x101F>(v[2 * m]);
        float o = swz_add<0x101F>(v[2 * m + 1]);
        w[m] = b2 ? o : e;
    }
    float s0 = swz_add<0x201F>(w[0]);
    float s1 = swz_add<0x201F>(w[1]);
    float S  = b3 ? s1 : s0;
    return swz_add<0x401F>(S);
}

// ---------------- transpose [t][c][h][w] -> [t][h][w][c], both vids ----------
// R14: float4 both sides. Load: lane=(c0=tid>>4, wq=(tid&15)*4) reads f4 along
// w -> 4x256B segments per wave-instr. Store: lane=(ww=tid>>4, cq=(tid&15)*4)
// writes f4 along c -> 1KB contiguous per wave-instr. LDS stride 65 -> 2-way
// bank aliasing only (free, m136).
__global__ __launch_bounds__(256) void transpose_k(
    const float* __restrict__ v0, const float* __restrict__ v1,
    float* __restrict__ ws)
{
    __shared__ float tile[64 * 65];
    const int wt  = blockIdx.x;      // 0..2  (w tile of 64)
    const int h   = blockIdx.y;      // 0..191
    const int z   = blockIdx.z;      // vid*4 + t
    const int vid = z >> 2;
    const int t   = z & 3;
    const int w0  = wt * 64;
    const int tid = threadIdx.x;
    const float* src = (vid ? v1 : v0) + (size_t)t * 64 * HW + h * WW + w0;
    float* dst = ws + (size_t)vid * TVID + ((size_t)(t * 192 + h) * 192 + w0) * 64;

    const int wq = (tid & 15) * 4;   // w quad
    const int c0 = tid >> 4;         // 0..15
    #pragma unroll
    for (int p = 0; p < 4; ++p) {
        const int cc = c0 + 16 * p;
        float4 v = *(const float4*)(src + (size_t)cc * HW + wq);
        tile[cc * 65 + wq + 0] = v.x;
        tile[cc * 65 + wq + 1] = v.y;
        tile[cc * 65 + wq + 2] = v.z;
        tile[cc * 65 + wq + 3] = v.w;
    }
    __syncthreads();
    const int cq  = (tid & 15) * 4;  // c quad
    const int ww0 = tid >> 4;        // 0..15
    #pragma unroll
    for (int p = 0; p < 4; ++p) {
        const int ww = ww0 + 16 * p;
        float4 v;
        v.x = tile[(cq + 0) * 65 + ww];
        v.y = tile[(cq + 1) * 65 + ww];
        v.z = tile[(cq + 2) * 65 + ww];
        v.w = tile[(cq + 3) * 65 + ww];
        *(float4*)(dst + ww * 64 + cq) = v;
    }
}

// ---------------- main kernel: barrier-free, continuous-stream prefetch -----
// (verbatim R12 -- proven passing at 246.7us)
__global__ __launch_bounds__(256) void nls_fast(
    const float* __restrict__ T0,
    const float* __restrict__ T1,
    float* __restrict__ out)
{
    __shared__ float score[2 * 192];

    // XCD swizzle: xcd = blk&7 -> qi band of 6; inner (hd, t, qi_l, qjp fastest)
    const int b    = blockIdx.x;
    const int xcd  = b & 7;
    const int loc  = b >> 3;
    const int qjp  = loc % 24;
    const int r1   = loc / 24;
    const int qi_l = r1 % 6;
    const int r2   = r1 / 6;
    const int t    = r2 & 3;
    const int hd   = r2 >> 2;
    const int qi   = xcd * 6 + qi_l;

    const int qh  = qi * 4;
    const int qw0 = qjp * 8;

    const int tid  = threadIdx.x;
    const int lane = tid & 63;
    const int wid  = tid >> 6;

    const int c     = lane & 31;
    const int hhalf = lane >> 5;   // dj half: 0 -> dj 0..3, 1 -> dj 4..7
    const int q     = wid >> 1;    // query in pair
    const int d     = wid & 1;     // di half: rows 4d..4d+3
    const int cg    = hd * 32 + c;
    const int qwq   = qw0 + 4 * q;

    // merge-reduce lane constants
    const bool b0 = (lane & 1) != 0;
    const bool b1 = (lane & 2) != 0;
    const bool b2 = (lane & 4) != 0;
    const bool b3 = (lane & 8) != 0;
    const bool writer = (lane & 16) == 0;   // lanes 0-15 and 32-47
    const int  kL   = lane & 15;
    const int  svoff = q * 192 + (4 * d + (kL >> 2)) * 8 + 4 * hhalf + (kL & 3);

    // ---- A patch -> regs (coalesced: 32 contiguous c per half-wave) ----
    float a[7][7];
    {
        #pragma unroll
        for (int y = 0; y < 7; ++y) {
            const int hv = reflect_i(qh - 3 + y, HH);
            const float* rp = T0 + (size_t)(t * 192 + hv) * ROWST + cg;
            #pragma unroll
            for (int x = 0; x < 7; ++x) {
                const int wv = reflect_i(qwq - 3 + x, WW);
                a[y][x] = rp[wv * 64];
            }
        }
    }

    const bool interior = (qi >= 2) && (qi <= 46) && (qjp >= 1) && (qjp <= 22);

    // exterior w-offsets (block-constant across tp)
    int wo[10];
    #pragma unroll
    for (int v = 0; v < 10; ++v)
        wo[v] = reflect_i(qwq - 6 + 4 * hhalf + v, WW) * 64 + cg;

    // x-outermost (R12): consecutive FMAs hit 16 different accs. Per-acc op
    // order unchanged (x ascending; mul-init first touch) -> bit-identical.
#define FMA_BLOCK(RWBUF)                                                 \
    {                                                                    \
        const int dlo = r > 6 ? r - 6 : 0;                               \
        const int dhi = r < 3 ? r : 3;                                   \
        _Pragma("unroll")                                                \
        for (int x = 0; x < 7; ++x) {                                    \
            _Pragma("unroll")                                            \
            for (int dip = 0; dip < 4; ++dip) {                          \
                if (dip >= dlo && dip <= dhi) {                          \
                    const int y = r - dip;                               \
                    _Pragma("unroll")                                    \
                    for (int djp = 0; djp < 4; ++djp) {                  \
                        if (y == 0 && x == 0)                            \
                            acc[dip * 4 + djp] = a[0][0] * (RWBUF)[djp]; \
                        else                                             \
                            acc[dip * 4 + djp] =                         \
                                fmaf(a[y][x], (RWBUF)[djp + x], acc[dip * 4 + djp]); \
                    }                                                    \
                }                                                        \
            }                                                            \
        }                                                                \
    }

    // ---- continuous row stream: rows of distinct tps are consecutive ----
    float rwb[2][10];
    float acc[16];
    float S = 0.f;

    const int tp0 = (t > 0) ? t - 1 : 0;

    // preload row 0 of tp0
    if (interior) {
        const float* P0 = T1 + (size_t)(tp0 * 192 + qh - 6 + 4 * d) * ROWST
                        + (qwq - 6 + 4 * hhalf) * 64 + cg;
        #pragma unroll
        for (int v = 0; v < 10; ++v) rwb[0][v] = P0[v * 64];
    } else {
        const int hv0 = reflect_i(qh - 6 + 4 * d, HH);
        const float* pr = T1 + (size_t)tp0 * TSLICE + (size_t)hv0 * ROWST;
        #pragma unroll
        for (int v = 0; v < 10; ++v) rwb[0][v] = pr[wo[v]];
    }

    int tprev = -1;
    #pragma unroll 1
    for (int dtI = 0; dtI < 3; ++dtI) {
        int tp = t + dtI - 1;
        tp = tp < 0 ? 0 : (tp > 3 ? 3 : tp);

        if (tp != tprev) {
            tprev = tp;

            if (interior) {
                const float* P = T1 + (size_t)(tp * 192 + qh - 6 + 4 * d) * ROWST
                               + (qwq - 6 + 4 * hhalf) * 64 + cg;
                const float* Pn0 = P + (tp < 3 ? TSLICE : 0);  // next tp, row 0
                #pragma unroll
                for (int r = 0; r < 10; ++r) {
                    const float* nrp = (r < 9) ? (P + (size_t)(r + 1) * ROWST) : Pn0;
                    #pragma unroll
                    for (int v = 0; v < 10; ++v)
                        rwb[(r + 1) & 1][v] = nrp[v * 64];
                    FMA_BLOCK(rwb[r & 1])
                }
            } else {
                const float* Ptb = T1 + (size_t)tp * TSLICE;
                const float* Ptn = (tp < 3) ? (Ptb + TSLICE) : Ptb;
                #pragma unroll
                for (int r = 0; r < 10; ++r) {
                    const int nr = (r < 9) ? r + 1 : 0;
                    const float* nb = (r < 9) ? Ptb : Ptn;
                    const int hv = reflect_i(qh - 6 + 4 * d + nr, HH);
                    const float* pr = nb + (size_t)hv * ROWST;
                    #pragma unroll
                    for (int v = 0; v < 10; ++v)
                        rwb[(r + 1) & 1][v] = pr[wo[v]];
                    FMA_BLOCK(rwb[r & 1])
                }
            }

            // c-reduction: lane L ends with 32-sum of acc[L&15] for its half
            S = merge_reduce(acc, b0, b1, b2, b3);
        }

        // write this dt's slot (dup dt writes same register -> exact ties)
        if (writer) score[svoff + dtI * 64] = S;
    }
#undef FMA_BLOCK

    __syncthreads();

    // ---- top-K=7 over 192 per query; waves 0,1 ----
    if (wid < 2) {
        const int qq = wid;
        const int qj = 2 * qjp + qq;
        float v0 = score[qq * 192 + lane];
        float v1 = score[qq * 192 + 64 + lane];
        float v2 = score[qq * 192 + 128 + lane];
        const int qglob = (t * 48 + qi) * 48 + qj;
        const int vbase = (hd * 9216 + qglob) * 7;
        const int ibase = 129024 + vbase * 3;
        for (int r = 0; r < 7; ++r) {
            float bv = v0; int bi = lane;
            if (v1 > bv) { bv = v1; bi = lane + 64; }
            if (v2 > bv) { bv = v2; bi = lane + 128; }
            #pragma unroll
            for (int m = 1; m <= 32; m <<= 1) {
                float ov = __shfl_xor(bv, m);
                int   oi = __shfl_xor(bi, m);
                if (ov > bv || (ov == bv && oi < bi)) { bv = ov; bi = oi; }
            }
            if (lane == 0) {
                out[vbase + r] = bv;
                int dtSel = bi >> 6;
                int rr    = bi & 63;
                int diSel = (rr >> 3) - 3;
                int djSel = (rr & 7) - 3;
                int ts = t + dtSel - 1;
                ts = ts < 0 ? 0 : (ts > 3 ? 3 : ts);
                int hs = reflect_i(qh + diSel, HH);
                int ws = reflect_i(qj * 4 + djSel, WW);
                float* op = out + ibase + 3 * r;
                op[0] = (float)ts;
                op[1] = (float)hs;
                op[2] = (float)ws;
            }
            if ((bi & 63) == lane) {
                int slot = bi >> 6;
                if (slot == 0)      v0 = -3.4e38f;
                else if (slot == 1) v1 = -3.4e38f;
                else                v2 = -3.4e38f;
            }
        }
    }
}

// ---------------- fallback (proven R5 kernel, 331 us) if ws too small --------
#define BS_CSTR 282
#define BS_SZ   (32 * BS_CSTR)
#define AF_CSTR 86

__global__ __launch_bounds__(256) void nls_kernel(
    const float* __restrict__ vid0,
    const float* __restrict__ vid1,
    float* __restrict__ out)
{
    __shared__ float smem[BS_SZ + 2 * 192];
    float* Bs = smem;
    float* Asf = smem;
    float* score = smem + BS_SZ;

    const int b    = blockIdx.x;
    const int xcd  = b & 7;
    const int loc  = b >> 3;
    const int qjp  = loc % 24;
    const int r1   = loc / 24;
    const int qi_l = r1 % 6;
    const int r2   = r1 / 6;
    const int t    = r2 & 3;
    const int hd   = r2 >> 2;
    const int qi   = xcd * 6 + qi_l;

    const int qh  = qi * 4;
    const int qw0 = qjp * 8;

    const int tid  = threadIdx.x;
    const int lane = tid & 63;
    const int wid  = tid >> 6;

    const bool intA = (qi >= 1) && (qjp >= 1) && (qjp <= 22);
    const bool intB = (qi >= 2) && (qi <= 46) && (qjp >= 1) && (qjp <= 22);

    if (intA) {
        const int sc = tid & 31;
        const int gg = tid >> 5;
        const float* src = vid0 + (size_t)(t * 64 + hd * 32 + sc) * HW
                         + (qh - 3) * WW + (qw0 - 3);
        float* dstc = Asf + sc * AF_CSTR;
        for (int it = gg; it < 21; it += 8) {
            int u = it / 3, grp = it - u * 3;
            float4 val = *(const float4*)(src + u * WW + 4 * grp);
            float* dp = dstc + u * 12 + 4 * grp;
            *(float2*)(dp)     = make_float2(val.x, val.y);
            *(float2*)(dp + 2) = make_float2(val.z, val.w);
        }
    } else {
        const int sc = tid >> 3;
        const int vl = tid & 7;
        const float* src = vid0 + (size_t)(t * 64 + hd * 32 + sc) * HW;
        const int wa0 = reflect_i(qw0 - 3 + vl, WW);
        const int wa1 = (vl < 4) ? reflect_i(qw0 + 5 + vl, WW) : 0;
        float* dst = Asf + sc * AF_CSTR + vl;
        #pragma unroll
        for (int u = 0; u < 7; ++u) {
            int hh = reflect_i(qh - 3 + u, HH);
            const float* rp = src + hh * WW;
            dst[u * 12] = rp[wa0];
            if (vl < 4) dst[u * 12 + 8] = rp[wa1];
        }
    }
    __syncthreads();

    const int c     = lane & 31;
    const int hhalf = lane >> 5;
    const int q     = wid >> 1;
    const int d     = wid & 1;

    float a[7][8];
    {
        const float* Ab = Asf + c * AF_CSTR + 4 * q;
        #pragma unroll
        for (int y = 0; y < 7; ++y) {
            #pragma unroll
            for (int j = 0; j < 4; ++j)
                *(float2*)&a[y][2 * j] = *(const float2*)(Ab + y * 12 + 2 * j);
        }
    }

    const float* Bc = Bs + c * BS_CSTR + (4 * d) * 20 + 4 * q + 4 * hhalf;

    int tprev = -1;
    #pragma unroll 1
    for (int dtI = 0; dtI < 3; ++dtI) {
        int tp = t + dtI - 1;
        tp = tp < 0 ? 0 : (tp > 3 ? 3 : tp);
        __syncthreads();
        if (tp == tprev) {
            if (tid < 128) {
                int qq = tid >> 6, o = tid & 63;
                score[qq * 192 + dtI * 64 + o] = score[qq * 192 + (dtI - 1) * 64 + o];
            }
            continue;
        }
        tprev = tp;

        if (intB) {
            const int sc = tid & 31;
            const int gg = tid >> 5;
            const float* src = vid1 + (size_t)(tp * 64 + hd * 32 + sc) * HW
                             + (qh - 6) * WW + (qw0 - 6);
            float* dstc = Bs + sc * BS_CSTR;
            for (int it = gg; it < 70; it += 8) {
                int u = it / 5, grp = it - u * 5;
                float4 val = *(const float4*)(src + u * WW + 4 * grp);
                float* dp = dstc + u * 20 + 4 * grp;
                *(float2*)(dp)     = make_float2(val.x, val.y);
                *(float2*)(dp + 2) = make_float2(val.z, val.w);
            }
        } else {
            const int sc = tid >> 3;
            const int vl = tid & 7;
            const float* src = vid1 + (size_t)(tp * 64 + hd * 32 + sc) * HW;
            const int w0 = reflect_i(qw0 - 6 + vl, WW);
            const int w1 = reflect_i(qw0 + 2 + vl, WW);
            const int w2 = (vl < 4) ? reflect_i(qw0 + 10 + vl, WW) : 0;
            float* dst = Bs + sc * BS_CSTR + vl;
            #pragma unroll
            for (int u = 0; u < 14; ++u) {
                int hh2 = reflect_i(qh - 6 + u, HH);
                const float* rp = src + hh2 * WW;
                dst[u * 20]     = rp[w0];
                dst[u * 20 + 8] = rp[w1];
                if (vl < 4) dst[u * 20 + 16] = rp[w2];
            }
        }
        __syncthreads();

        {
            float acc[16];
            #pragma unroll
            for (int k = 0; k < 16; ++k) acc[k] = 0.f;
            #pragma unroll
            for (int r = 0; r < 10; ++r) {
                float rw[12];
                const float* Br = Bc + r * 20;
                #pragma unroll
                for (int j = 0; j < 6; ++j)
                    *(float2*)&rw[2 * j] = *(const float2*)(Br + 2 * j);
                const int dlo = r > 6 ? r - 6 : 0;
                const int dhi = r < 3 ? r : 3;
                #pragma unroll
                for (int dip = 0; dip < 4; ++dip) {
                    if (dip >= dlo && dip <= dhi) {
                        const int y = r - dip;
                        #pragma unroll
                        for (int djp = 0; djp < 4; ++djp)
                            #pragma unroll
                            for (int x = 0; x < 7; ++x)
                                acc[dip * 4 + djp] =
                                    fmaf(a[y][x], rw[djp + x], acc[dip * 4 + djp]);
                    }
                }
            }
            #pragma unroll
            for (int k = 0; k < 16; ++k) acc[k] = reduce32(acc[k]);
            if ((lane & 31) == 31) {
                float* sp = &score[q * 192 + dtI * 64 + 4 * hhalf];
                #pragma unroll
                for (int dip = 0; dip < 4; ++dip) {
                    float* dp = sp + (4 * d + dip) * 8;
                    *(float2*)(dp)     = make_float2(acc[dip * 4 + 0], acc[dip * 4 + 1]);
                    *(float2*)(dp + 2) = make_float2(acc[dip * 4 + 2], acc[dip * 4 + 3]);
                }
            }
        }
    }

    __syncthreads();

    if (wid < 2) {
        const int qq = wid;
        const int qj = 2 * qjp + qq;
        float v0 = score[qq * 192 + lane];
        float v1 = score[qq * 192 + 64 + lane];
        float v2 = score[qq * 192 + 128 + lane];
        const int qglob = (t * 48 + qi) * 48 + qj;
        const int vbase = (hd * 9216 + qglob) * 7;
        const int ibase = 129024 + vbase * 3;
        for (int r = 0; r < 7; ++r) {
            float bv = v0; int bi = lane;
            if (v1 > bv) { bv = v1; bi = lane + 64; }
            if (v2 > bv) { bv = v2; bi = lane + 128; }
            #pragma unroll
            for (int m = 1; m <= 32; m <<= 1) {
                float ov = __shfl_xor(bv, m);
                int   oi = __shfl_xor(bi, m);
                if (ov > bv || (ov == bv && oi < bi)) { bv = ov; bi = oi; }
            }
            if (lane == 0) {
                out[vbase + r] = bv;
                int dtSel = bi >> 6;
                int rr    = bi & 63;
                int diSel = (rr >> 3) - 3;
                int djSel = (rr & 7) - 3;
                int ts = t + dtSel - 1;
                ts = ts < 0 ? 0 : (ts > 3 ? 3 : ts);
                int hs = reflect_i(qh + diSel, HH);
                int ws = reflect_i(qj * 4 + djSel, WW);
                float* op = out + ibase + 3 * r;
                op[0] = (float)ts;
                op[1] = (float)hs;
                op[2] = (float)ws;
            }
            if ((bi & 63) == lane) {
                int slot = bi >> 6;
                if (slot == 0)      v0 = -3.4e38f;
                else if (slot == 1) v1 = -3.4e38f;
                else                v2 = -3.4e38f;
            }
        }
    }
}

extern "C" void kernel_launch(void* const* d_in, const int* in_sizes, int n_in,
                              void* d_out, int out_size, void* d_ws, size_t ws_size,
                              hipStream_t stream) {
    const float* vid0 = (const float*)d_in[0];
    const float* vid1 = (const float*)d_in[1];
    float* out = (float*)d_out;
    const size_t need = 2ull * (size_t)TVID * sizeof(float);   // 75.5 MB
    if (ws_size >= need) {
        float* ws = (float*)d_ws;
        transpose_k<<<dim3(3, 192, 8), 256, 0, stream>>>(vid0, vid1, ws);
        nls_fast<<<dim3(9216), 256, 0, stream>>>(ws, ws + TVID, out);
    } else {
        nls_kernel<<<dim3(9216), 256, 0, stream>>>(vid0, vid1, out);
    }
}